// Round 15
// baseline (265.851 us; speedup 1.0000x reference)
//
#include <hip/hip_runtime.h>
#include <hip/hip_bf16.h>
#include <math.h>

// augGNN collapse (measured r14: 250us; r12: 316us; r8: 335us; r5: 573us):
//   gin1: u_n = x_n + sum_in x_src; gin2 agg -> per-dst {Su+, Su-, #pos, deg} per column;
//   post-ReLU linearity folded into G1,G2 (64x6) + C0; relu -> @Wl2 -> log_softmax.
// r14 post-mortem: fusion hid the 122us precompute (net -66us) BUT static 28KB LDS is
//   allocated for ALL blocks -> occupancy 55%->30% -> edge scatter 120->170us.
// r15 change: slim precompute LDS to 8.2KB (drop W4T/Wl1s; G1/G2 loop reads global,
//   L1-cached, 1 hidden block). Edge path should recover ~55% occupancy / ~120us.
// ws layout (4B units): deg[N] | csr[S*N] | u[2N floats] | cst[1094]

#define BN_EPS 1e-5f

__global__ __launch_bounds__(256) void fused_build(
    const int* __restrict__ ei, int* __restrict__ deg, int* __restrict__ csr,
    int E, int N, int S,
    const float* __restrict__ W1, const float* __restrict__ b1,
    const float* __restrict__ g1, const float* __restrict__ be1,
    const float* __restrict__ W2, const float* __restrict__ b2,
    const float* __restrict__ W3, const float* __restrict__ b3,
    const float* __restrict__ g2, const float* __restrict__ be2,
    const float* __restrict__ W4, const float* __restrict__ b4,
    const float* __restrict__ Wl1, const float* __restrict__ bl1,
    float* __restrict__ cst) {
  // 8.2 KB total — keeps edge-block occupancy at the wave cap, not LDS cap.
  __shared__ float sa[256], sc[256];
  __shared__ float part[4][2][128];
  __shared__ float vap[128], van[128], vcp[128], vcn[128];
  int t = threadIdx.x;

  if (blockIdx.x == 0) {
    // ---- precompute path (1 block, hidden under ~120us of edge blocks) ----
    const float inv = 1.0f / sqrtf(1.0f + BN_EPS);
    sa[t] = g1[t] * W1[t] * inv;
    sc[t] = g1[t] * b1[t] * inv + be1[t];
    __syncthreads();
    {
      int k = t & 127, h = t >> 7;
      float ap = 0.f, an = 0.f, cp = 0.f, cn = 0.f;
      int j0 = h * 128;
      for (int jj = 0; jj < 128; ++jj) {
        int j = j0 + jj;
        float w = W2[j * 128 + k];  // coalesced across k
        float aj = sa[j], cj = sc[j];
        if (aj > 0.f)      { ap += aj * w; cp += cj * w; }
        else if (aj < 0.f) { an += aj * w; cn += cj * w; }
        else if (cj > 0.f) { cp += cj * w; cn += cj * w; }  // a==0: relu(c) const
      }
      part[0][h][k] = ap; part[1][h][k] = an; part[2][h][k] = cp; part[3][h][k] = cn;
    }
    __syncthreads();
    if (t < 128) {
      float bk = b2[t];
      vap[t] = part[0][0][t] + part[0][1][t];
      van[t] = part[1][0][t] + part[1][1][t];
      vcp[t] = part[2][0][t] + part[2][1][t] + bk;
      vcn[t] = part[3][0][t] + part[3][1][t] + bk;
    }
    __syncthreads();
    if (t < 64) {
      float pa = 0.f, na = 0.f, pc = 0.f, nc = 0.f;
      for (int k = 0; k < 128; ++k) {
        float w = W3[k * 64 + t];   // coalesced across t
        pa += vap[k] * w; na += van[k] * w; pc += vcp[k] * w; nc += vcn[k] * w;
      }
      float f = g2[t] * inv;
      cst[t]       = f * pa;             // PA'
      cst[64 + t]  = f * na;             // NA'
      cst[128 + t] = f * pc;             // PC'
      cst[192 + t] = f * nc;             // NC'
      cst[256 + t] = f * b3[t] + be2[t]; // beta
    }
    for (int idx = t; idx < 384; idx += 256) {   // G1/G2 from global (L1-cached)
      int m = idx / 6, r = idx - m * 6;
      float s1 = 0.f, s2 = 0.f;
      for (int q = 0; q < 64; ++q) {
        float w4 = W4[m * 64 + q];
        s1 += w4 * Wl1[q * 6 + r];
        s2 += w4 * Wl1[(64 + q) * 6 + r];
      }
      cst[320 + idx] = s1;               // G1
      cst[704 + idx] = s2;               // G2
    }
    if (t < 6) {
      float s = bl1[t];
      for (int q = 0; q < 64; ++q)
        s += b4[q] * (Wl1[q * 6 + t] + Wl1[(64 + q) * 6 + t]);
      cst[1088 + t] = s;                 // C0
    }
    return;
  }

  // ---- edge path: slot-major CSR build, 1 atomic per edge ----
  int i4 = (blockIdx.x - 1) * 256 + t;
  int base = i4 * 4;
  if (base + 3 < E) {
    int4 sv = *reinterpret_cast<const int4*>(ei + base);
    int4 dv = *reinterpret_cast<const int4*>(ei + E + base);
    #pragma unroll
    for (int k = 0; k < 4; ++k) {
      int s = (&sv.x)[k];
      int d = (&dv.x)[k];
      int p = atomicAdd(&deg[d], 1);
      if (p < S) csr[(size_t)p * N + d] = s;
    }
  } else {
    for (int i = base; i < E; ++i) {
      int s = ei[i];
      int d = ei[E + i];
      int p = atomicAdd(&deg[d], 1);
      if (p < S) csr[(size_t)p * N + d] = s;
    }
  }
}

// u[n] = x[n] + sum over in-neighbors x[src]. Plane-wise coalesced gather.
__global__ __launch_bounds__(256) void reduce_u(
    const float* __restrict__ x, const int* __restrict__ deg,
    const int* __restrict__ csr, float* __restrict__ u, int N, int S) {
  int n = blockIdx.x * blockDim.x + threadIdx.x;
  if (n >= N) return;
  int dg = deg[n]; if (dg > S) dg = S; if (dg < 0) dg = 0;
  float a0 = 0.f, a1 = 0.f;
  int p = 0;
  for (; p + 3 < dg; p += 4) {
    int s0 = csr[(size_t)p * N + n];
    int s1 = csr[(size_t)(p + 1) * N + n];
    int s2 = csr[(size_t)(p + 2) * N + n];
    int s3 = csr[(size_t)(p + 3) * N + n];
    float2 p0 = *reinterpret_cast<const float2*>(x + 2 * (size_t)s0);
    float2 p1 = *reinterpret_cast<const float2*>(x + 2 * (size_t)s1);
    float2 p2 = *reinterpret_cast<const float2*>(x + 2 * (size_t)s2);
    float2 p3 = *reinterpret_cast<const float2*>(x + 2 * (size_t)s3);
    a0 += (p0.x + p1.x) + (p2.x + p3.x);
    a1 += (p0.y + p1.y) + (p2.y + p3.y);
  }
  for (; p < dg; ++p) {
    int s = csr[(size_t)p * N + n];
    float2 pv = *reinterpret_cast<const float2*>(x + 2 * (size_t)s);
    a0 += pv.x; a1 += pv.y;
  }
  float2 xv = *reinterpret_cast<const float2*>(x + 2 * (size_t)n);
  float2 uv; uv.x = xv.x + a0; uv.y = xv.y + a1;
  *reinterpret_cast<float2*>(u + 2 * (size_t)n) = uv;
}

// Second reduce + full tail math fused. Counts come free (no atomics).
__global__ __launch_bounds__(256) void reduce_final(
    const float* __restrict__ u, const int* __restrict__ deg,
    const int* __restrict__ csr, const float* __restrict__ cst,
    const float* __restrict__ Wl2, const float* __restrict__ bl2,
    float* __restrict__ out, int N, int S) {
  __shared__ float C[1136];
  int t = threadIdx.x;
  for (int i = t; i < 1094; i += 256) C[i] = cst[i];
  if (t < 36) C[1094 + t] = Wl2[t];
  if (t < 6)  C[1130 + t] = bl2[t];
  __syncthreads();
  const float* PA = C;        const float* NA = C + 64;
  const float* PC = C + 128;  const float* NC = C + 192;
  const float* B  = C + 256;
  const float* G1 = C + 320;  const float* G2 = C + 704;
  const float* C0 = C + 1088; const float* W2s = C + 1094;
  const float* b2s = C + 1130;

  int n = blockIdx.x * blockDim.x + t;
  if (n >= N) return;

  int dg = deg[n]; if (dg > S) dg = S; if (dg < 0) dg = 0;
  float cp1 = 0.f, cn1 = 0.f, cp0 = 0.f, cn0 = 0.f;
  int np1i = 0, np0i = 0;
  int p = 0;
  for (; p + 3 < dg; p += 4) {
    int s0 = csr[(size_t)p * N + n];
    int s1 = csr[(size_t)(p + 1) * N + n];
    int s2 = csr[(size_t)(p + 2) * N + n];
    int s3 = csr[(size_t)(p + 3) * N + n];
    #pragma unroll
    for (int k = 0; k < 4; ++k) {
      int s = (k == 0) ? s0 : (k == 1) ? s1 : (k == 2) ? s2 : s3;
      float2 uv = *reinterpret_cast<const float2*>(u + 2 * (size_t)s);
      if (uv.y > 0.f) { cp1 += uv.y; ++np1i; } else cn1 += uv.y;
      if (uv.x > 0.f) { cp0 += uv.x; ++np0i; } else cn0 += uv.x;
    }
  }
  for (; p < dg; ++p) {
    int s = csr[(size_t)p * N + n];
    float2 uv = *reinterpret_cast<const float2*>(u + 2 * (size_t)s);
    if (uv.y > 0.f) { cp1 += uv.y; ++np1i; } else cn1 += uv.y;
    if (uv.x > 0.f) { cp0 += uv.x; ++np0i; } else cn0 += uv.x;
  }
  float2 us = *reinterpret_cast<const float2*>(u + 2 * (size_t)n);
  float degp1 = (float)dg + 1.0f;

  float o[6];
  #pragma unroll
  for (int r = 0; r < 6; ++r) o[r] = C0[r];

  // column 1 -> e1 -> G1
  {
    float uu = us.y;
    float cp = cp1 + fmaxf(uu, 0.f);
    float cn = cn1 + fminf(uu, 0.f);
    float np = (float)np1i + ((uu > 0.f) ? 1.f : 0.f);
    float nn = degp1 - np;
    #pragma unroll 8
    for (int m = 0; m < 64; ++m) {
      float y = fmaxf(fmaf(cp, PA[m], fmaf(cn, NA[m], fmaf(np, PC[m], fmaf(nn, NC[m], B[m])))), 0.f);
      #pragma unroll
      for (int r = 0; r < 6; ++r) o[r] = fmaf(y, G1[m * 6 + r], o[r]);
    }
  }
  // column 0 -> e2 -> G2
  {
    float uu = us.x;
    float cp = cp0 + fmaxf(uu, 0.f);
    float cn = cn0 + fminf(uu, 0.f);
    float np = (float)np0i + ((uu > 0.f) ? 1.f : 0.f);
    float nn = degp1 - np;
    #pragma unroll 8
    for (int m = 0; m < 64; ++m) {
      float y = fmaxf(fmaf(cp, PA[m], fmaf(cn, NA[m], fmaf(np, PC[m], fmaf(nn, NC[m], B[m])))), 0.f);
      #pragma unroll
      for (int r = 0; r < 6; ++r) o[r] = fmaf(y, G2[m * 6 + r], o[r]);
    }
  }

  float tq[6];
  #pragma unroll
  for (int r = 0; r < 6; ++r) tq[r] = fmaxf(o[r], 0.f);
  float v[6];
  #pragma unroll
  for (int r = 0; r < 6; ++r) {
    float s = b2s[r];
    #pragma unroll
    for (int q = 0; q < 6; ++q) s = fmaf(tq[q], W2s[q * 6 + r], s);
    v[r] = s;
  }
  float mx = v[0];
  #pragma unroll
  for (int r = 1; r < 6; ++r) mx = fmaxf(mx, v[r]);
  float ssum = 0.f;
  #pragma unroll
  for (int r = 0; r < 6; ++r) ssum += expf(v[r] - mx);
  float lse = mx + logf(ssum);
  #pragma unroll
  for (int r = 0; r < 6; ++r) out[6 * (size_t)n + r] = v[r] - lse;
}

extern "C" void kernel_launch(void* const* d_in, const int* in_sizes, int n_in,
                              void* d_out, int out_size, void* d_ws, size_t ws_size,
                              hipStream_t stream) {
  const float* x   = (const float*)d_in[0];
  const int*   ei  = (const int*)d_in[1];
  const float* W1  = (const float*)d_in[2];
  const float* b1  = (const float*)d_in[3];
  const float* g1  = (const float*)d_in[4];
  const float* be1 = (const float*)d_in[5];
  const float* W2  = (const float*)d_in[6];
  const float* b2  = (const float*)d_in[7];
  const float* W3  = (const float*)d_in[8];
  const float* b3  = (const float*)d_in[9];
  const float* g2  = (const float*)d_in[10];
  const float* be2 = (const float*)d_in[11];
  const float* W4  = (const float*)d_in[12];
  const float* b4  = (const float*)d_in[13];
  const float* Wl1 = (const float*)d_in[14];
  const float* bl1 = (const float*)d_in[15];
  const float* Wl2 = (const float*)d_in[16];
  const float* bl2 = (const float*)d_in[17];
  float* out = (float*)d_out;

  const int N = in_sizes[0] / 2;
  const int E = in_sizes[1] / 2;

  // Plane ladder: S=64 (27MB) preferred; degrade if ws_size is tight.
  int S = 64;
  {
    size_t fixed = (size_t)N /*deg*/ + 2 * (size_t)N /*u*/ + 1200 /*cst*/;
    if ((fixed + (size_t)N * 64) * 4 > ws_size) S = 48;
    if ((fixed + (size_t)N * 48) * 4 > ws_size) S = 32;
  }

  int*   deg = (int*)d_ws;                     // N ints
  int*   csr = deg + N;                        // S*N ints (slot-major planes)
  float* u   = (float*)(csr + (size_t)N * S);  // 2N floats
  float* cst = u + 2 * (size_t)N;              // 1094 floats

  const int tb = 256;
  const int E4 = (E + 3) / 4;
  const int egrid = (E4 + tb - 1) / tb;
  hipMemsetAsync(deg, 0, (size_t)N * sizeof(int), stream);
  hipLaunchKernelGGL(fused_build, dim3(egrid + 1), dim3(tb), 0, stream,
                     ei, deg, csr, E, N, S,
                     W1, b1, g1, be1, W2, b2, W3, b3, g2, be2, W4, b4, Wl1, bl1, cst);
  hipLaunchKernelGGL(reduce_u, dim3((N + tb - 1) / tb), dim3(tb), 0, stream,
                     x, deg, csr, u, N, S);
  hipLaunchKernelGGL(reduce_final, dim3((N + tb - 1) / tb), dim3(tb), 0, stream,
                     u, deg, csr, cst, Wl2, bl2, out, N, S);
}